// Round 2
// baseline (46.533 us; speedup 1.0000x reference)
//
#include <hip/hip_runtime.h>
#include <stdint.h>
#include <stddef.h>

typedef _Float16 f16;
typedef _Float16 f16x2 __attribute__((ext_vector_type(2)));
typedef _Float16 f16x4 __attribute__((ext_vector_type(4)));
typedef _Float16 f16x8 __attribute__((ext_vector_type(8)));
typedef float f32x4 __attribute__((ext_vector_type(4)));

#define INNER_SZ 4225
#define WK 4224          // padded K for Wf: 4096 quad + 64 linear + 64 zero
#define KQ 4096

// ---------------- prep: fold ones-column, cast W to f16 ----------------
__global__ __launch_bounds__(256) void cm_prep(const float* __restrict__ W,
                                               const float* __restrict__ bias,
                                               f16* __restrict__ Wf,
                                               float* __restrict__ cvec) {
  int idx = blockIdx.x * 256 + threadIdx.x;
  if (idx < 64 * WK) {
    int o = idx / WK;
    int k = idx - o * WK;
    float v;
    if (k < KQ) {                       // quadratic: coeff of x_i * x_j
      int i = k >> 6, j = k & 63;
      v = W[o * INNER_SZ + (i + 1) * 65 + (j + 1)];
    } else if (k < KQ + 64) {           // linear: coeff of x_j
      int j = k - KQ;
      v = W[o * INNER_SZ + (j + 1)] + W[o * INNER_SZ + (j + 1) * 65];
    } else {
      v = 0.f;                          // pad
    }
    Wf[idx] = (f16)v;
  }
  if (idx < 64) cvec[idx] = W[idx * INNER_SZ] + bias[idx];  // const + bias
}

// global -> LDS direct, 16B/lane (dest is wave-uniform base + lane*16)
__device__ inline void gload_lds16(const void* g, void* l) {
  __builtin_amdgcn_global_load_lds(
      (const __attribute__((address_space(1))) uint32_t*)(uintptr_t)g,
      (__attribute__((address_space(3))) uint32_t*)(uintptr_t)l, 16, 0, 0);
}

// ---------------- main fused kernel ----------------
// grid 512, block 256 (4 waves). M_TILE=128. wave (mg,ng): rows mg*64+[0,64), cols ng*32+[0,32)
__global__ __launch_bounds__(256, 2) void cm_main(
    const float* __restrict__ x, const f16* __restrict__ Wf,
    const float* __restrict__ cvec, const float* __restrict__ gamma,
    const float* __restrict__ beta, float* __restrict__ out) {
  __shared__ __align__(16) f16 xs[128 * 72];          // x tile f16, stride 72 (bank-friendly)
  __shared__ __align__(16) f16 wlds[2][64 * 128];     // W chunk double buffer, [o][128k], XOR-swizzled
  __shared__ float part[2][128][2];                   // per-row (sum,sumsq) per N-half

  const int tid = threadIdx.x;
  const int lane = tid & 63;
  const int wid = tid >> 6;
  const int mg = wid & 1;
  const int ng = wid >> 1;
  const int g = lane >> 4;
  const int c15 = lane & 15;
  const int mbase = blockIdx.x * 128;

  // ---- stage W chunk 0 into buf 0 (pre-swizzled source, linear LDS dest) ----
  {
#pragma unroll
    for (int jj = 0; jj < 4; ++jj) {
      int j = wid * 4 + jj;                 // 16 x 1KB instrs over 4 waves
      int cl = j * 4 + g;                   // W row (output col) 0..63
      int soff = (c15 * 16) ^ ((cl & 7) << 4);
      gload_lds16(Wf + (size_t)cl * WK + (soff >> 1), &wlds[0][j * 512]);
    }
  }

  // ---- x tile -> LDS f16 [128][72] ----
#pragma unroll
  for (int it = 0; it < 8; ++it) {
    int off = it * 1024 + tid * 4;
    int row = off >> 6;
    int col = off & 63;
    const float4 v = *(const float4*)(x + (size_t)(mbase + row) * 64 + col);
    f16x4 h = {(f16)v.x, (f16)v.y, (f16)v.z, (f16)v.w};
    *(f16x4*)(xs + row * 72 + col) = h;
  }
  __syncthreads();

  // ---- gather per-lane j-windows: xjv[mf][p] = x[row, p*32 + g*8 .. +7] ----
  f16x8 xjv[4][2];
#pragma unroll
  for (int mf = 0; mf < 4; ++mf) {
    int row = mg * 64 + mf * 16 + c15;
#pragma unroll
    for (int p = 0; p < 2; ++p)
      xjv[mf][p] = *(const f16x8*)(xs + row * 72 + p * 32 + g * 8);
  }

  f32x4 acc[4][2];
#pragma unroll
  for (int mf = 0; mf < 4; ++mf)
#pragma unroll
    for (int nf = 0; nf < 2; ++nf)
      acc[mf][nf] = (f32x4){0.f, 0.f, 0.f, 0.f};

  // ---- K loop: 32 chunks x 4 ksteps (quadratic part), double-buffered ----
  for (int t = 0; t < 32; ++t) {
    {
      int bi = (t + 1) & 1;
#pragma unroll
      for (int jj = 0; jj < 4; ++jj) {
        int j = wid * 4 + jj;
        int cl = j * 4 + g;
        int soff = (c15 * 16) ^ ((cl & 7) << 4);
        gload_lds16(Wf + (size_t)cl * WK + (t + 1) * 128 + (soff >> 1),
                    &wlds[bi][j * 512]);
      }
    }
    // x_i scalars for i = 2t, 2t+1 (wave-uniform index, per-lane row)
    f16x2 xi2[4];
#pragma unroll
    for (int mf = 0; mf < 4; ++mf) {
      int row = mg * 64 + mf * 16 + c15;
      xi2[mf] = *(const f16x2*)(xs + row * 72 + 2 * t);
    }
    const char* wb = (const char*)&wlds[t & 1][0];
#pragma unroll
    for (int s = 0; s < 4; ++s) {
      f16x8 bf[2];
#pragma unroll
      for (int nf = 0; nf < 2; ++nf) {
        int col = ng * 32 + nf * 16 + c15;
        int kb = s * 64 + g * 16;
        bf[nf] = *(const f16x8*)(wb + col * 256 + (kb ^ ((c15 & 7) << 4)));
      }
#pragma unroll
      for (int mf = 0; mf < 4; ++mf) {
        f16 xv = xi2[mf][s >> 1];
        f16x8 xi8 = {xv, xv, xv, xv, xv, xv, xv, xv};
        f16x8 a = xi8 * xjv[mf][s & 1];   // 4x v_pk_mul_f16: A = x_i * x_jwindow
        acc[mf][0] = __builtin_amdgcn_mfma_f32_16x16x32_f16(a, bf[0], acc[mf][0], 0, 0, 0);
        acc[mf][1] = __builtin_amdgcn_mfma_f32_16x16x32_f16(a, bf[1], acc[mf][1], 0, 0, 0);
      }
    }
    __syncthreads();
  }

  // ---- tail chunk 32 (linear part, k'=4096..4159): A = x_j directly ----
  {
    const char* wb = (const char*)&wlds[0][0];
#pragma unroll
    for (int s = 0; s < 2; ++s) {
      f16x8 bf[2];
#pragma unroll
      for (int nf = 0; nf < 2; ++nf) {
        int col = ng * 32 + nf * 16 + c15;
        int kb = s * 64 + g * 16;
        bf[nf] = *(const f16x8*)(wb + col * 256 + (kb ^ ((c15 & 7) << 4)));
      }
#pragma unroll
      for (int mf = 0; mf < 4; ++mf) {
        f16x8 a = xjv[mf][s];
        acc[mf][0] = __builtin_amdgcn_mfma_f32_16x16x32_f16(a, bf[0], acc[mf][0], 0, 0, 0);
        acc[mf][1] = __builtin_amdgcn_mfma_f32_16x16x32_f16(a, bf[1], acc[mf][1], 0, 0, 0);
      }
    }
  }

  // ---- epilogue: +const, LayerNorm over 64 outputs, store f32 ----
  float cv[2], gv[2], bv[2];
#pragma unroll
  for (int nf = 0; nf < 2; ++nf) {
    int col = ng * 32 + nf * 16 + c15;
    cv[nf] = cvec[col];
    gv[nf] = gamma[col];
    bv[nf] = beta[col];
  }
  float yv[4][2][4];
#pragma unroll
  for (int mf = 0; mf < 4; ++mf)
#pragma unroll
    for (int nf = 0; nf < 2; ++nf)
#pragma unroll
      for (int r = 0; r < 4; ++r)
        yv[mf][nf][r] = acc[mf][nf][r] + cv[nf];

  // D layout: col = lane&15, row = (lane>>4)*4 + r.  Reduce over cols (16 lanes, same g).
#pragma unroll
  for (int mf = 0; mf < 4; ++mf) {
#pragma unroll
    for (int r = 0; r < 4; ++r) {
      float s = yv[mf][0][r] + yv[mf][1][r];
      float q = yv[mf][0][r] * yv[mf][0][r] + yv[mf][1][r] * yv[mf][1][r];
#pragma unroll
      for (int m = 1; m <= 8; m <<= 1) {
        s += __shfl_xor(s, m);
        q += __shfl_xor(q, m);
      }
      if (c15 == 0) {
        int lr = mg * 64 + mf * 16 + g * 4 + r;
        part[ng][lr][0] = s;
        part[ng][lr][1] = q;
      }
    }
  }
  __syncthreads();
#pragma unroll
  for (int mf = 0; mf < 4; ++mf) {
#pragma unroll
    for (int r = 0; r < 4; ++r) {
      int lr = mg * 64 + mf * 16 + g * 4 + r;
      float s = part[0][lr][0] + part[1][lr][0];
      float q = part[0][lr][1] + part[1][lr][1];
      float mean = s * 0.015625f;
      float var = q * 0.015625f - mean * mean;
      float rstd = rsqrtf(var + 1e-6f);
#pragma unroll
      for (int nf = 0; nf < 2; ++nf) {
        int col = ng * 32 + nf * 16 + c15;
        out[(size_t)(mbase + lr) * 64 + col] =
            gv[nf] * (yv[mf][nf][r] - mean) * rstd + bv[nf];
      }
    }
  }
}

extern "C" void kernel_launch(void* const* d_in, const int* in_sizes, int n_in,
                              void* d_out, int out_size, void* d_ws, size_t ws_size,
                              hipStream_t stream) {
  const float* x     = (const float*)d_in[0];
  const float* W     = (const float*)d_in[1];
  const float* bias  = (const float*)d_in[2];
  const float* gamma = (const float*)d_in[3];
  const float* beta  = (const float*)d_in[4];
  float* out = (float*)d_out;

  f16* Wf = (f16*)d_ws;                                  // 64*4224*2 = 540672 B
  float* cvec = (float*)((char*)d_ws + 64 * WK * 2);     // 64 f32

  cm_prep<<<(64 * WK + 255) / 256, 256, 0, stream>>>(W, bias, Wf, cvec);
  cm_main<<<512, 256, 0, stream>>>(x, Wf, cvec, gamma, beta, out);
}